// Round 15
// baseline (142.239 us; speedup 1.0000x reference)
//
#include <hip/hip_runtime.h>
#include <cstddef>
#include <cstdint>

#define FN_ 100000
#define V_  50000
#define B_  8
// 100000 = 3125 * 32 -> each wave owns exactly 32 columns (128B store lines).
#define WPB   8                     // waves per block (512 threads)
#define NBLK  3125                  // 25000 wave-tiles / 8

// d_ws layout (bytes) — ALL weight reads in main are per-use global (L2-hot):
//   0     : L1 K16 weights, 16 tiles x 512B (16 rows x 16 k, frag-ordered)
//           rows 0-63 c1, 64-127 e0, 128-191 e1, 192-255 e2; k semantics:
//           0-8 = corner verts, 9-11 = center, 12 = folded BN shift (X[12]=1)
//   8192  : c2, 8 tiles x 1KB (K32 frag order)
//   16384 : v2, 8 tiles x 1KB (x1/3 folded)
//   24576 : s,  16 tiles x 1KB   (ends at 40960)
//   40960 : shs f32[448] (256 c2, 320 v2, 384 s)
#define WS_SHS_OFF 40960

typedef _Float16 f16;
typedef f16   f16x4 __attribute__((ext_vector_type(4)));
typedef f16   f16x8 __attribute__((ext_vector_type(8)));
typedef float f32x4 __attribute__((ext_vector_type(4)));

struct Ptrs { const void* p[33]; };

union Pk4h { f16 h[4]; uint2 u; };
union Pk8 { f16 h[8]; uint4 u; };
union FragU4 { uint32_t u[2]; f16x4 v; };

__device__ __forceinline__ uint32_t pack2(float a, float b) {
  return __builtin_bit_cast(uint32_t, __builtin_amdgcn_cvt_pkrtz(a, b));
}
__device__ __forceinline__ uint32_t pack_relu2(float a, float b) {
  uint32_t r, x = pack2(a, b);
  asm("v_pk_max_f16 %0, %1, 0" : "=v"(r) : "v"(x));
  return r;
}

// ---------------- prep: fold BN into f16 weights, fragment-ordered ----------------
// (R13/R14 layout; K32 loop bound FIXED to 2048 — 2560 overwrote shsG with
//  tiles 32-33 and read OOB of sw; masked in this test only because all BN
//  shifts are zero and f16-pair garbage reads as ~1e-13 f32.)
__global__ __launch_bounds__(1024) void sd_prep(Ptrs in, f16* __restrict__ wsW,
                                                float* __restrict__ shsG)
{
  const float* __restrict__ cw1 = (const float*)in.p[3];
  const float* __restrict__ cb1 = (const float*)in.p[4];
  const float* __restrict__ c1g = (const float*)in.p[5];
  const float* __restrict__ c1bt= (const float*)in.p[6];
  const float* __restrict__ c1m = (const float*)in.p[7];
  const float* __restrict__ c1v = (const float*)in.p[8];
  const float* __restrict__ cw2 = (const float*)in.p[9];
  const float* __restrict__ cb2 = (const float*)in.p[10];
  const float* __restrict__ c2g = (const float*)in.p[11];
  const float* __restrict__ c2bt= (const float*)in.p[12];
  const float* __restrict__ c2m = (const float*)in.p[13];
  const float* __restrict__ c2v = (const float*)in.p[14];
  const float* __restrict__ vw1 = (const float*)in.p[15];
  const float* __restrict__ vb1 = (const float*)in.p[16];
  const float* __restrict__ v1g = (const float*)in.p[17];
  const float* __restrict__ v1bt= (const float*)in.p[18];
  const float* __restrict__ v1m = (const float*)in.p[19];
  const float* __restrict__ v1v = (const float*)in.p[20];
  const float* __restrict__ vw2 = (const float*)in.p[21];
  const float* __restrict__ vb2 = (const float*)in.p[22];
  const float* __restrict__ v2g = (const float*)in.p[23];
  const float* __restrict__ v2bt= (const float*)in.p[24];
  const float* __restrict__ v2m = (const float*)in.p[25];
  const float* __restrict__ v2v = (const float*)in.p[26];
  const float* __restrict__ sw  = (const float*)in.p[27];
  const float* __restrict__ sb  = (const float*)in.p[28];
  const float* __restrict__ s1g = (const float*)in.p[29];
  const float* __restrict__ s1bt= (const float*)in.p[30];
  const float* __restrict__ s1m = (const float*)in.p[31];
  const float* __restrict__ s1v = (const float*)in.p[32];

  __shared__ float scsL[448];
  __shared__ float shfL[256];       // L1 shifts for the bias-column trick
  const int tid = threadIdx.x;

  if (tid < 448) {
    const float *g, *v, *bb, *m, *bt; int o; float mul = 1.f;
    if (tid < 64)       { o = tid;      g=c1g; v=c1v; bb=cb1; m=c1m; bt=c1bt; }
    else if (tid < 256) { o = tid & 63; g=v1g; v=v1v; bb=vb1; m=v1m; bt=v1bt; }
    else if (tid < 320) { o = tid-256;  g=c2g; v=c2v; bb=cb2; m=c2m; bt=c2bt; }
    else if (tid < 384) { o = tid-320;  g=v2g; v=v2v; bb=vb2; m=v2m; bt=v2bt; mul = 1.f/3.f; }
    else                { o = tid-384;  g=s1g; v=s1v; bb=sb;  m=s1m; bt=s1bt; }
    float s = g[o] * rsqrtf(v[o] + 1e-5f);
    float sh = ((bb[o] - m[o]) * s + bt[o]) * mul;
    scsL[tid] = s * mul;
    shsG[tid] = sh;
    if (tid < 256) shfL[tid] = sh;
  }
  __syncthreads();

  // ---- L1 K16 region: 16 tiles x 512B, one 8B unit per thread ----
  {
    const int t = tid >> 6, l = tid & 63, r15l = l & 15, g4l = l >> 4;
    const int row = 16*t + r15l;
    const int wm = t >> 2;
    Pk4h pk;
#pragma unroll
    for (int j = 0; j < 4; ++j) {
      const int k = 4*g4l + j; float val = 0.f;
      if (wm == 0) { if (k >= 9 && k < 12) val = cw1[row*3 + (k-9)]; }
      else if (k < 9) {
        const int e = wm - 1, o = row - 64*wm, c = (k - 3*e + 9) % 9;
        if (c < 6) val = vw1[o*6 + c];
      }
      pk.h[j] = (k == 12) ? (f16)shfL[row] : (f16)(val * scsL[row]);
    }
    *(uint2*)((char*)wsW + t*512 + l*8) = pk.u;
  }

  // ---- K32 region: 32 tiles (c2 0-7, v2 8-15, s 16-31) at byte 8192 ----
  for (int u = tid; u < 2048; u += 1024) {
    const int t = u >> 6, l = u & 63, r15l = l & 15, g4l = l >> 4;
    Pk8 pk;
    if (t < 8) {                                    // c2
      const int rt = t >> 1, s = t & 1, row = 16*rt + r15l;
#pragma unroll
      for (int j = 0; j < 8; ++j) { const int k = 32*s + 8*g4l + j;
        pk.h[j] = (f16)(cw2[row*64 + k] * scsL[256+row]); }
    } else if (t < 16) {                            // v2 (x 1/3)
      const int tt = t-8, rt = tt >> 1, s = tt & 1, row = 16*rt + r15l;
#pragma unroll
      for (int j = 0; j < 8; ++j) { const int k = 32*s + 8*g4l + j;
        pk.h[j] = (f16)(vw2[row*64 + k] * scsL[320+row]); }
    } else {                                        // s (64x128)
      const int tt = t-16, rt = tt >> 2, s4 = tt & 3, row = 16*rt + r15l;
#pragma unroll
      for (int j = 0; j < 8; ++j) { const int k = 32*s4 + 8*g4l + j;
        pk.h[j] = (f16)(sw[row*128 + k] * scsL[384+row]); }
    }
    *(uint4*)((char*)wsW + 8192 + t*1024 + l*16) = pk.u;
  }
}

// ---------------- main: wave-autonomous, ZERO barriers ----------------
// All weights per-use from global (L2-hot, 48 KB). Ab = 32 cols x 128 k per
// wave: k0..63 = L1 scratch (then vf), k64..127 = cf (written at br0).
// No persistent weight registers (R13/R14 spill lesson).
__global__ __launch_bounds__(512, 4) void sd_main(const int* __restrict__ faces,
    const float* __restrict__ verts, const float* __restrict__ centers,
    const f16* __restrict__ wsW, const float* __restrict__ shsG,
    float* __restrict__ out)
{
  __shared__ f16 Ab[WPB][32 * 128];    // 64 KB total; stride 256B ≡ 0 mod 32 banks

  const int tid  = threadIdx.x;
  const int lane = tid & 63;
  const int r15  = lane & 15;
  const int g4   = lane >> 4;
  const int w    = __builtin_amdgcn_readfirstlane(tid >> 6);
  const int sw   = (r15 & 7) << 3;

  // wave-tile: wt in [0,25000); by = wt/3125, f0 = (wt%3125)*32
  const int wt = blockIdx.x * WPB + w;
  const int by = wt / 3125;
  const int f0 = (wt - by * 3125) * 32;

  // ---- gather X (K16 layout: lane holds k = 4*g4 + j) — validated R13/R14 ----
  FragU4 xf[2];
#pragma unroll
  for (int c = 0; c < 2; ++c) {
    float vals[4] = {0.f, 0.f, 0.f, 0.f};
    const int f = f0 + 16*c + r15;
    const size_t fb3 = ((size_t)by*FN_ + f)*3;
    if (g4 == 0) {            // k0-3: v0.x v0.y v0.z v1.x
      const int i0 = faces[fb3], i1 = faces[fb3+1];
      const float* q0 = verts + ((size_t)by*V_ + (size_t)i0)*3;
      const float* q1 = verts + ((size_t)by*V_ + (size_t)i1)*3;
      vals[0]=q0[0]; vals[1]=q0[1]; vals[2]=q0[2]; vals[3]=q1[0];
    } else if (g4 == 1) {     // k4-7: v1.y v1.z v2.x v2.y
      const int i1 = faces[fb3+1], i2 = faces[fb3+2];
      const float* q1 = verts + ((size_t)by*V_ + (size_t)i1)*3;
      const float* q2 = verts + ((size_t)by*V_ + (size_t)i2)*3;
      vals[0]=q1[1]; vals[1]=q1[2]; vals[2]=q2[0]; vals[3]=q2[1];
    } else if (g4 == 2) {     // k8-11: v2.z c.x c.y c.z
      const int i2 = faces[fb3+2];
      const float* q2 = verts + ((size_t)by*V_ + (size_t)i2)*3;
      vals[0]=q2[2];
      vals[1]=centers[((size_t)by*3+0)*FN_ + f];
      vals[2]=centers[((size_t)by*3+1)*FN_ + f];
      vals[3]=centers[((size_t)by*3+2)*FN_ + f];
    } else {                  // k12-15: bias 1, zeros
      vals[0]=1.0f;
    }
    xf[c].u[0] = pack2(vals[0], vals[1]);
    xf[c].u[1] = pack2(vals[2], vals[3]);
  }

  f16* ab = &Ab[w][0];
  float vf[4][2][4];

  // ================== branch quarters: br0=c1/c2, br1..3=edge/v2 ==================
#pragma unroll
  for (int br = 0; br < 4; ++br) {
    // ---- L1 quarter: K16 MFMAs, A-frags per-use global (b64, L2-hot) ----
    f32x4 acc1[4][2];
#pragma unroll
    for (int t4 = 0; t4 < 4; ++t4) {
      const f16x4 a = *(const f16x4*)((const char*)wsW + (4*br + t4)*512 + lane*8);
#pragma unroll
      for (int c = 0; c < 2; ++c) {
        f32x4 z = {0.f,0.f,0.f,0.f};
        acc1[t4][c] = __builtin_amdgcn_mfma_f32_16x16x16f16(a, xf[c].v, z, 0,0,0);
      }
    }
#pragma unroll
    for (int t4 = 0; t4 < 4; ++t4)
#pragma unroll
      for (int c = 0; c < 2; ++c) {
        uint2 pw;
        pw.x = pack_relu2(acc1[t4][c][0], acc1[t4][c][1]);
        pw.y = pack_relu2(acc1[t4][c][2], acc1[t4][c][3]);
        *(uint2*)&ab[(16*c + r15)*128 + ((16*t4 + 4*g4) ^ sw)] = pw;
      }

    // ---- L2 quarter (intra-wave DS order, no barrier) ----
    f16x8 b2[2][2];
#pragma unroll
    for (int c = 0; c < 2; ++c)
#pragma unroll
      for (int s = 0; s < 2; ++s)
        b2[c][s] = *(const f16x8*)&ab[(16*c + r15)*128 + ((32*s + 8*g4) ^ sw)];

    const int wbase = br ? 16384 : 8192;
    const int shb   = br ? 320 : 256;
#pragma unroll
    for (int rt = 0; rt < 4; ++rt) {
      const f16x8 a0 = *(const f16x8*)((const char*)wsW + wbase + (2*rt    )*1024 + lane*16);
      const f16x8 a1 = *(const f16x8*)((const char*)wsW + wbase + (2*rt + 1)*1024 + lane*16);
      const f32x4 shv = *(const f32x4*)&shsG[shb + rt*16 + 4*g4];
#pragma unroll
      for (int c = 0; c < 2; ++c) {
        f32x4 acc = __builtin_amdgcn_mfma_f32_16x16x32_f16(a0, b2[c][0], shv, 0,0,0);
        acc = __builtin_amdgcn_mfma_f32_16x16x32_f16(a1, b2[c][1], acc, 0,0,0);
        if (br == 0) {
          // cf -> Ab k64..127 immediately (frees register state)
          uint2 pw;
          pw.x = pack_relu2(acc[0], acc[1]);
          pw.y = pack_relu2(acc[2], acc[3]);
          *(uint2*)&ab[(16*c + r15)*128 + 64 + ((16*rt + 4*g4) ^ sw)] = pw;
        } else if (br == 1) {
#pragma unroll
          for (int j = 0; j < 4; ++j) vf[rt][c][j] = fmaxf(acc[j], 0.f);
        } else {
#pragma unroll
          for (int j = 0; j < 4; ++j) vf[rt][c][j] += fmaxf(acc[j], 0.f);
        }
      }
    }
  }

  // ---- vf -> Ab k0..63 (L1 scratch now dead; intra-wave DS order) ----
#pragma unroll
  for (int rt = 0; rt < 4; ++rt)
#pragma unroll
    for (int c = 0; c < 2; ++c) {
      uint2 pw;
      pw.x = pack2(vf[rt][c][0], vf[rt][c][1]);
      pw.y = pack2(vf[rt][c][2], vf[rt][c][3]);
      *(uint2*)&ab[(16*c + r15)*128 + ((16*rt + 4*g4) ^ sw)] = pw;
    }

  // ================== L3: cv = [cf @ k64..127 ; vf @ k0..63] ==================
  f32x4 acc3[4][2];
#pragma unroll
  for (int rt = 0; rt < 4; ++rt) {
    const f32x4 shv = *(const f32x4*)&shsG[384 + rt*16 + 4*g4];
    acc3[rt][0] = shv; acc3[rt][1] = shv;
  }

#pragma unroll
  for (int half = 0; half < 2; ++half) {
    const int kb = half ? 0 : 64;       // half0 reads cf (k64..), half1 reads vf (k0..)
#pragma unroll
    for (int s = 0; s < 2; ++s) {
      f16x8 b[2];
#pragma unroll
      for (int c = 0; c < 2; ++c)
        b[c] = *(const f16x8*)&ab[(16*c + r15)*128 + kb + ((32*s + 8*g4) ^ sw)];
#pragma unroll
      for (int rt = 0; rt < 4; ++rt) {
        const f16x8 aS = *(const f16x8*)((const char*)wsW + 24576
                                         + (4*rt + 2*half + s)*1024 + lane*16);
        acc3[rt][0] = __builtin_amdgcn_mfma_f32_16x16x32_f16(aS, b[0], acc3[rt][0], 0,0,0);
        acc3[rt][1] = __builtin_amdgcn_mfma_f32_16x16x32_f16(aS, b[1], acc3[rt][1], 0,0,0);
      }
    }
  }

  // ---- stores (32 consecutive cols per wave per row -> full 128B lines) ----
#pragma unroll
  for (int rt = 0; rt < 4; ++rt)
#pragma unroll
    for (int c = 0; c < 2; ++c) {
      const size_t base = ((size_t)(by*64 + rt*16 + 4*g4))*FN_ + (size_t)(f0 + 16*c + r15);
#pragma unroll
      for (int j = 0; j < 4; ++j)
        out[base + (size_t)j*FN_] = fmaxf(acc3[rt][c][j], 0.f);
    }
}

extern "C" void kernel_launch(void* const* d_in, const int* in_sizes, int n_in,
                              void* d_out, int out_size, void* d_ws, size_t ws_size,
                              hipStream_t stream) {
  (void)in_sizes; (void)n_in; (void)out_size; (void)ws_size;
  Ptrs p;
  for (int i = 0; i < 33; ++i) p.p[i] = d_in[i];
  f16*   wsW  = (f16*)d_ws;
  float* shsG = (float*)((char*)d_ws + WS_SHS_OFF);
  hipLaunchKernelGGL(sd_prep, dim3(1), dim3(1024), 0, stream, p, wsW, shsG);
  hipLaunchKernelGGL(sd_main, dim3(NBLK), dim3(512), 0, stream,
                     (const int*)d_in[2], (const float*)d_in[1], (const float*)d_in[0],
                     wsW, shsG, (float*)d_out);
}